// Round 8
// baseline (204.103 us; speedup 1.0000x reference)
//
#include <hip/hip_runtime.h>
#include <hip/hip_cooperative_groups.h>
#include <math.h>

namespace cg = cooperative_groups;

// InfiniteContextAttention — causal mask reaches only keys 0..15 (= compressed_k/v[:,:, :16]).
// Pipeline: q = hidden @ Wq^T -> 16-key causal attention -> out = attn @ Wo^T.
//
// v8 = v7 (37.4us) with EXACTLY ONE change: the 4 kernels are fused into one
// cooperative kernel with grid.sync() between phases (bodies verbatim).
// Rationale: depth-3 prefetch was a clean null -> K-loop is not the residual;
// ~5-8us of the 37.4 is dispatch gaps + small-kernel overhead (attn ~3us,
// reduce ~1.5us are mostly launch cost). 512 blocks x 256 thr co-resident:
// LDS 32KB (<=5 blk/CU), launch_bounds(256,2) -> 2 blk/CU x 256 CU = 512. 

#define HID 4096
#define NROW 32
#define NSLICE 8
#define KSL 512
#define NSTEP 16
#define PART_STRIDE (NROW * HID)  // 131072 floats per slice

typedef __attribute__((ext_vector_type(8))) short short8;
typedef __attribute__((ext_vector_type(4))) float f32x4;

__device__ __forceinline__ unsigned short bf16_rne(float x) {
    union { float f; unsigned u; } c; c.f = x;
    unsigned u = c.u;
    return (unsigned short)((u + 0x7fffu + ((u >> 16) & 1u)) >> 16);
}

// ---- v7 gemm body, verbatim (A fp32 -> swizzled bf16 LDS; W streamed; K-split partials) ----
__device__ __forceinline__ void gemm_body(const float* __restrict__ A,
                                          const float* __restrict__ W,
                                          float* __restrict__ P,
                                          short* As, int bid, int tid)
{
    const int lane = tid & 63;
    const int wv   = tid >> 6;
    const int cg_  = bid & 63;      // column group (64 cols)
    const int sl   = bid >> 6;      // K-slice 0..7
    const int ks   = sl * KSL;

    {
        const int r  = tid >> 3;
        const int c8 = tid & 7;
        const float* src = A + (size_t)r * HID + ks + c8 * 4;
        char* lb = (char*)As + r * (KSL * 2);
        const int rx = (r & 7) << 4;
#pragma unroll
        for (int i = 0; i < 16; ++i) {
            float4 v = *(const float4*)(src + i * 32);
            unsigned long long pk =
                  (unsigned long long)bf16_rne(v.x)
                | ((unsigned long long)bf16_rne(v.y) << 16)
                | ((unsigned long long)bf16_rne(v.z) << 32)
                | ((unsigned long long)bf16_rne(v.w) << 48);
            int byte = ((c8 + 8 * i) * 8) ^ rx;
            *(unsigned long long*)(lb + byte) = pk;
        }
    }
    __syncthreads();

    const int l15 = lane & 15, lq = lane >> 4, l7 = lane & 7;
    const int jcol = cg_ * 64 + wv * 16 + l15;
    const float* wp = W + (size_t)jcol * HID + ks + lq * 8;
    const char* lA0 = (const char*)As + l15 * (KSL * 2);
    const char* lA1 = (const char*)As + (16 + l15) * (KSL * 2);
    const int rswz = l7 << 4;

    f32x4 acc0 = {0.f, 0.f, 0.f, 0.f}, acc1 = {0.f, 0.f, 0.f, 0.f};

    float4 w0a = *(const float4*)(wp);
    float4 w0b = *(const float4*)(wp + 4);
    float4 w1a = *(const float4*)(wp + 32);
    float4 w1b = *(const float4*)(wp + 36);
    float4 w2a = *(const float4*)(wp + 64);
    float4 w2b = *(const float4*)(wp + 68);

#pragma unroll
    for (int kk = 0; kk < NSTEP; ++kk) {
        float4 nA = {}, nB = {};
        if (kk < NSTEP - 3) {
            nA = *(const float4*)(wp + (kk + 3) * 32);
            nB = *(const float4*)(wp + (kk + 3) * 32 + 4);
        }
        const int byte = ((kk * 64) + (lq * 16)) ^ rswz;
        short8 a0 = *(const short8*)(lA0 + byte);
        short8 a1 = *(const short8*)(lA1 + byte);
        short8 b;
        b[0] = (short)bf16_rne(w0a.x); b[1] = (short)bf16_rne(w0a.y);
        b[2] = (short)bf16_rne(w0a.z); b[3] = (short)bf16_rne(w0a.w);
        b[4] = (short)bf16_rne(w0b.x); b[5] = (short)bf16_rne(w0b.y);
        b[6] = (short)bf16_rne(w0b.z); b[7] = (short)bf16_rne(w0b.w);
        acc0 = __builtin_amdgcn_mfma_f32_16x16x32_bf16(a0, b, acc0, 0, 0, 0);
        acc1 = __builtin_amdgcn_mfma_f32_16x16x32_bf16(a1, b, acc1, 0, 0, 0);
        w0a = w1a; w0b = w1b; w1a = w2a; w1b = w2b; w2a = nA; w2b = nB;
    }

    float* pout = P + (size_t)sl * PART_STRIDE + jcol;
#pragma unroll
    for (int rr = 0; rr < 4; ++rr) {
        pout[(size_t)(lq * 4 + rr) * HID]      = acc0[rr];
        pout[(size_t)(16 + lq * 4 + rr) * HID] = acc1[rr];
    }
}

// ---- v7 attn body, verbatim (8-slice q-reduce fused; one wave per (b,h,i)) ----
__device__ __forceinline__ void attn_body(const float* __restrict__ P,
                                          const float* __restrict__ ck,
                                          const float* __restrict__ cv,
                                          float* __restrict__ o,
                                          int bid, int tid)
{
    const int lane = tid & 63;
    const int g = bid * 4 + (tid >> 6);  // 0..1023
    const int b = g >> 9;
    const int h = (g >> 4) & 31;
    const int i = g & 15;

    const size_t qoff = ((size_t)(b * 16 + i)) * HID + h * 128 + 2 * lane;
    float2 q2 = {0.f, 0.f};
#pragma unroll
    for (int s = 0; s < NSLICE; ++s) {
        float2 p = *(const float2*)(P + (size_t)s * PART_STRIDE + qoff);
        q2.x += p.x; q2.y += p.y;
    }
    const size_t kvoff = ((size_t)(b * 32 + h)) * 2048 * 128 + 2 * lane;
    const float* kp = ck + kvoff;
    const float* vp = cv + kvoff;

    float e[16];
#pragma unroll
    for (int s = 0; s < 16; ++s) {
        float2 k2 = *(const float2*)(kp + (size_t)s * 128);
        float p = q2.x * k2.x + q2.y * k2.y;
#pragma unroll
        for (int m = 32; m >= 1; m >>= 1) p += __shfl_xor(p, m, 64);
        e[s] = (s <= i) ? p * 0.08838834764831845f : -3.4e38f;  // i wave-uniform
    }
    float mx = e[0];
#pragma unroll
    for (int s = 1; s < 16; ++s) mx = fmaxf(mx, e[s]);
    float den = 0.f;
#pragma unroll
    for (int s = 0; s < 16; ++s) { e[s] = __expf(e[s] - mx); den += e[s]; }
    const float inv = 1.0f / den;

    float ox = 0.f, oy = 0.f;
#pragma unroll
    for (int s = 0; s < 16; ++s) {
        float2 v2 = *(const float2*)(vp + (size_t)s * 128);
        ox += e[s] * v2.x;
        oy += e[s] * v2.y;
    }
    float2 res; res.x = ox * inv; res.y = oy * inv;
    *(float2*)(o + qoff) = res;
}

// ---- fused cooperative kernel: gemm1 | attn | gemm2 | reduce ----
__global__ __launch_bounds__(256, 2)
void fused_kernel(const float* __restrict__ hidden,
                  const float* __restrict__ ck,
                  const float* __restrict__ cv,
                  const float* __restrict__ Wq,
                  const float* __restrict__ Wo,
                  float* __restrict__ out,
                  float* __restrict__ part,
                  float* __restrict__ abuf)
{
    __shared__ short As[NROW * KSL];  // 32 KB, reused by both gemm phases
    cg::grid_group grid = cg::this_grid();
    const int tid = threadIdx.x;
    const int bid = blockIdx.x;

    gemm_body(hidden, Wq, part, As, bid, tid);       // q partials
    grid.sync();

    if (bid < 256) attn_body(part, ck, cv, abuf, bid, tid);
    grid.sync();

    gemm_body(abuf, Wo, part, As, bid, tid);         // out partials (part reuse safe)
    grid.sync();

    if (bid < 128) {                                 // v7 reduce body, verbatim
        const int idx = bid * 256 + tid;
        const float4* p4 = (const float4*)part;
        float4 s = p4[idx];
#pragma unroll
        for (int t = 1; t < NSLICE; ++t) {
            float4 v = p4[idx + t * (PART_STRIDE / 4)];
            s.x += v.x; s.y += v.y; s.z += v.z; s.w += v.w;
        }
        ((float4*)out)[idx] = s;
    }
}

extern "C" void kernel_launch(void* const* d_in, const int* in_sizes, int n_in,
                              void* d_out, int out_size, void* d_ws, size_t ws_size,
                              hipStream_t stream) {
    const float* hidden = (const float*)d_in[0];  // [2][16][4096]
    const float* ck     = (const float*)d_in[3];  // [2][32][2048][128]
    const float* cv     = (const float*)d_in[4];
    const float* Wq     = (const float*)d_in[5];  // [4096][4096]
    const float* Wo     = (const float*)d_in[8];
    float* out  = (float*)d_out;                  // [2][16][4096]
    float* part = (float*)d_ws;                   // [8][32][4096] = 4 MB
    float* abuf = part + NSLICE * PART_STRIDE;    // [32][4096] attn output

    void* args[] = { (void*)&hidden, (void*)&ck, (void*)&cv, (void*)&Wq,
                     (void*)&Wo, (void*)&out, (void*)&part, (void*)&abuf };
    hipLaunchCooperativeKernel((void*)fused_kernel, dim3(512), dim3(256),
                               args, 0, stream);
}

// Round 9
// 95.788 us; speedup vs baseline: 2.1308x; 2.1308x over previous
//
#include <hip/hip_runtime.h>
#include <math.h>

// InfiniteContextAttention — causal mask reaches only keys 0..15 (= compressed_k/v[:,:, :16]).
// Pipeline: q = hidden @ Wq^T -> 16-key causal attention -> out = attn @ Wo^T.
//
// v9 = v7 (37.4us) with EXACTLY ONE change: reduce8_kernel is fused into gemm2
// as a deterministic ticket fan-in (last of the 8 K-slice blocks per column
// group sums slices in fixed order -> bit-deterministic). 3 dispatches, not 4.
// v8 lesson: cooperative fusion starves registers (VGPR 64, scratch spill) — avoid.

#define HID 4096
#define NROW 32
#define NSLICE 8
#define KSL 512
#define NSTEP 16
#define PART_STRIDE (NROW * HID)  // 131072 floats per slice

typedef __attribute__((ext_vector_type(8))) short short8;
typedef __attribute__((ext_vector_type(4))) float f32x4;

__device__ __forceinline__ unsigned short bf16_rne(float x) {
    union { float f; unsigned u; } c; c.f = x;
    unsigned u = c.u;
    return (unsigned short)((u + 0x7fffu + ((u >> 16) & 1u)) >> 16);
}

template<bool FINAL>
__global__ __launch_bounds__(256, 2)
void gemm_mfma(const float* __restrict__ A,   // [32][4096] fp32
               const float* __restrict__ W,   // [4096][4096] fp32
               float* __restrict__ P,         // [8][32][4096] fp32 partials
               float* __restrict__ Cout,      // [32][4096] final (FINAL only)
               int* __restrict__ tickets)     // [64]; reset by the !FINAL pass
{
    __shared__ short As[NROW * KSL];  // 32 KB bf16, XOR-swizzled (T2)
    const int tid  = threadIdx.x;
    const int lane = tid & 63;
    const int wv   = tid >> 6;            // wave 0..3 -> 16-col tile
    const int cg   = blockIdx.x & 63;     // column group (64 cols)
    const int sl   = blockIdx.x >> 6;     // K-slice 0..7
    const int ks   = sl * KSL;

    if (!FINAL && blockIdx.x < 64 && tid == 0) tickets[blockIdx.x] = 0;

    // ---- stage A slice (fp32 -> bf16, swizzled), coalesced 128B-granule reads ----
    {
        const int r  = tid >> 3;          // row 0..31
        const int c8 = tid & 7;           // float4 column subgroup
        const float* src = A + (size_t)r * HID + ks + c8 * 4;
        char* lb = (char*)As + r * (KSL * 2);
        const int rx = (r & 7) << 4;
#pragma unroll
        for (int i = 0; i < 16; ++i) {
            float4 v = *(const float4*)(src + i * 32);
            unsigned long long pk =
                  (unsigned long long)bf16_rne(v.x)
                | ((unsigned long long)bf16_rne(v.y) << 16)
                | ((unsigned long long)bf16_rne(v.z) << 32)
                | ((unsigned long long)bf16_rne(v.w) << 48);
            int byte = ((c8 + 8 * i) * 8) ^ rx;
            *(unsigned long long*)(lb + byte) = pk;
        }
    }
    __syncthreads();  // the only barrier: LDS written once

    const int l15 = lane & 15, lq = lane >> 4, l7 = lane & 7;
    const int jcol = cg * 64 + wv * 16 + l15;
    const float* wp = W + (size_t)jcol * HID + ks + lq * 8;
    const char* lA0 = (const char*)As + l15 * (KSL * 2);
    const char* lA1 = (const char*)As + (16 + l15) * (KSL * 2);
    const int rswz = l7 << 4;

    f32x4 acc0 = {0.f, 0.f, 0.f, 0.f}, acc1 = {0.f, 0.f, 0.f, 0.f};

    // depth-3 rolling W prefetch (round-7 null: keep, harmless)
    float4 w0a = *(const float4*)(wp);
    float4 w0b = *(const float4*)(wp + 4);
    float4 w1a = *(const float4*)(wp + 32);
    float4 w1b = *(const float4*)(wp + 36);
    float4 w2a = *(const float4*)(wp + 64);
    float4 w2b = *(const float4*)(wp + 68);

#pragma unroll
    for (int kk = 0; kk < NSTEP; ++kk) {
        float4 nA = {}, nB = {};
        if (kk < NSTEP - 3) {
            nA = *(const float4*)(wp + (kk + 3) * 32);
            nB = *(const float4*)(wp + (kk + 3) * 32 + 4);
        }
        const int byte = ((kk * 64) + (lq * 16)) ^ rswz;
        short8 a0 = *(const short8*)(lA0 + byte);
        short8 a1 = *(const short8*)(lA1 + byte);
        short8 b;
        b[0] = (short)bf16_rne(w0a.x); b[1] = (short)bf16_rne(w0a.y);
        b[2] = (short)bf16_rne(w0a.z); b[3] = (short)bf16_rne(w0a.w);
        b[4] = (short)bf16_rne(w0b.x); b[5] = (short)bf16_rne(w0b.y);
        b[6] = (short)bf16_rne(w0b.z); b[7] = (short)bf16_rne(w0b.w);
        acc0 = __builtin_amdgcn_mfma_f32_16x16x32_bf16(a0, b, acc0, 0, 0, 0);
        acc1 = __builtin_amdgcn_mfma_f32_16x16x32_bf16(a1, b, acc1, 0, 0, 0);
        w0a = w1a; w0b = w1b; w1a = w2a; w1b = w2b; w2a = nA; w2b = nB;
    }

    // ---- partial store: C/D layout col=lane&15, row=(lane>>4)*4+reg (m89) ----
    float* pout = P + (size_t)sl * PART_STRIDE + jcol;
#pragma unroll
    for (int rr = 0; rr < 4; ++rr) {
        pout[(size_t)(lq * 4 + rr) * HID]      = acc0[rr];
        pout[(size_t)(16 + lq * 4 + rr) * HID] = acc1[rr];
    }

    if (FINAL) {
        // deterministic fan-in: last K-slice block of this column group reduces.
        __threadfence();                 // release: my partials -> device scope
        __shared__ int winS;
        __syncthreads();                 // all threads of block have fenced
        if (tid == 0)
            winS = (atomicAdd(&tickets[cg], 1) == NSLICE - 1);
        __syncthreads();
        if (!winS) return;
        __threadfence();                 // acquire: see all 8 slices

        const int j   = cg * 64 + (tid & 63);
        const int rr0 = tid >> 6;        // 4 waves x 8 rows each
#pragma unroll
        for (int rr = rr0; rr < NROW; rr += 4) {
            float s = 0.f;
#pragma unroll
            for (int t = 0; t < NSLICE; ++t)   // fixed order -> bit-deterministic
                s += P[(size_t)t * PART_STRIDE + (size_t)rr * HID + j];
            Cout[(size_t)rr * HID + j] = s;
        }
    }
}

// One wave per (b,h,i): fuses the 8-slice q-reduction with 16-key causal attention.
__global__ __launch_bounds__(256)
void attn16_kernel(const float* __restrict__ P,   // q partials [8][32][4096]
                   const float* __restrict__ ck,
                   const float* __restrict__ cv,
                   float* __restrict__ o)          // [32][4096]
{
    const int lane = threadIdx.x & 63;
    const int g = blockIdx.x * 4 + (threadIdx.x >> 6);  // 0..1023
    const int b = g >> 9;
    const int h = (g >> 4) & 31;
    const int i = g & 15;

    const size_t qoff = ((size_t)(b * 16 + i)) * HID + h * 128 + 2 * lane;
    float2 q2 = {0.f, 0.f};
#pragma unroll
    for (int s = 0; s < NSLICE; ++s) {
        float2 p = *(const float2*)(P + (size_t)s * PART_STRIDE + qoff);
        q2.x += p.x; q2.y += p.y;
    }
    const size_t kvoff = ((size_t)(b * 32 + h)) * 2048 * 128 + 2 * lane;
    const float* kp = ck + kvoff;
    const float* vp = cv + kvoff;

    float e[16];
#pragma unroll
    for (int s = 0; s < 16; ++s) {
        float2 k2 = *(const float2*)(kp + (size_t)s * 128);
        float p = q2.x * k2.x + q2.y * k2.y;
#pragma unroll
        for (int m = 32; m >= 1; m >>= 1) p += __shfl_xor(p, m, 64);
        e[s] = (s <= i) ? p * 0.08838834764831845f : -3.4e38f;  // i wave-uniform
    }
    float mx = e[0];
#pragma unroll
    for (int s = 1; s < 16; ++s) mx = fmaxf(mx, e[s]);
    float den = 0.f;
#pragma unroll
    for (int s = 0; s < 16; ++s) { e[s] = __expf(e[s] - mx); den += e[s]; }
    const float inv = 1.0f / den;

    float ox = 0.f, oy = 0.f;
#pragma unroll
    for (int s = 0; s < 16; ++s) {
        float2 v2 = *(const float2*)(vp + (size_t)s * 128);
        ox += e[s] * v2.x;
        oy += e[s] * v2.y;
    }
    float2 res; res.x = ox * inv; res.y = oy * inv;
    *(float2*)(o + qoff) = res;
}

extern "C" void kernel_launch(void* const* d_in, const int* in_sizes, int n_in,
                              void* d_out, int out_size, void* d_ws, size_t ws_size,
                              hipStream_t stream) {
    const float* hidden = (const float*)d_in[0];  // [2][16][4096]
    const float* ck     = (const float*)d_in[3];  // [2][32][2048][128]
    const float* cv     = (const float*)d_in[4];
    const float* Wq     = (const float*)d_in[5];  // [4096][4096]
    const float* Wo     = (const float*)d_in[8];
    float* out = (float*)d_out;                   // [2][16][4096]

    char* ws = (char*)d_ws;
    float* part    = (float*)ws;                              // 4 MB partials
    float* abuf    = (float*)(ws + (4u << 20));               // 512 KB attn out
    int*   tickets = (int*)(ws + (4u << 20) + (512u << 10));  // 256 B

    hipLaunchKernelGGL((gemm_mfma<false>), dim3(512), dim3(256), 0, stream,
                       hidden, Wq, part, (float*)nullptr, tickets);
    hipLaunchKernelGGL(attn16_kernel,      dim3(256), dim3(256), 0, stream,
                       part, ck, cv, abuf);
    hipLaunchKernelGGL((gemm_mfma<true>),  dim3(512), dim3(256), 0, stream,
                       abuf, Wo, part, out, tickets);
}

// Round 10
// 37.491 us; speedup vs baseline: 5.4440x; 2.5549x over previous
//
#include <hip/hip_runtime.h>
#include <math.h>

// InfiniteContextAttention — causal mask reaches only keys 0..15 (= compressed_k/v[:,:, :16]).
// Pipeline: q = hidden @ Wq^T -> 16-key causal attention -> out = attn @ Wo^T.
//
// v10 = v7 (37.4us, proven) with EXACTLY ONE change: the depth-3 W prologue is
// issued BEFORE the A-staging loop, so the W HBM stream is in flight during
// staging (~1-1.5us bubble) and the first MFMA doesn't pay a cold HBM latency.
// v9 lesson: device-scope fences (ticket fan-in) cost ~58us on 8-XCD CDNA4 — never again.
// v8 lesson: cooperative fusion starves VGPRs (spill). 4-dispatch structure stands.

#define HID 4096
#define NROW 32
#define NSLICE 8
#define KSL 512
#define NSTEP 16
#define PART_STRIDE (NROW * HID)  // 131072 floats per slice

typedef __attribute__((ext_vector_type(8))) short short8;
typedef __attribute__((ext_vector_type(4))) float f32x4;

__device__ __forceinline__ unsigned short bf16_rne(float x) {
    union { float f; unsigned u; } c; c.f = x;
    unsigned u = c.u;
    return (unsigned short)((u + 0x7fffu + ((u >> 16) & 1u)) >> 16);
}

__global__ __launch_bounds__(256, 2)
void gemm_mfma(const float* __restrict__ A,   // [32][4096] fp32
               const float* __restrict__ W,   // [4096][4096] fp32
               float* __restrict__ P)         // [8][32][4096] fp32 partials
{
    __shared__ short As[NROW * KSL];  // 32 KB bf16, XOR-swizzled (T2)
    const int tid  = threadIdx.x;
    const int lane = tid & 63;
    const int wv   = tid >> 6;            // wave 0..3 -> 16-col tile
    const int cg   = blockIdx.x & 63;     // column group (64 cols)
    const int sl   = blockIdx.x >> 6;     // K-slice 0..7
    const int ks   = sl * KSL;

    const int l15 = lane & 15, lq = lane >> 4, l7 = lane & 7;
    const int jcol = cg * 64 + wv * 16 + l15;
    const float* wp = W + (size_t)jcol * HID + ks + lq * 8;

    // ---- ONLY CHANGE vs v7: depth-3 W prologue issued BEFORE staging ----
    // (W stream in flight while we stage A; fills the pre-barrier HBM bubble)
    float4 w0a = *(const float4*)(wp);
    float4 w0b = *(const float4*)(wp + 4);
    float4 w1a = *(const float4*)(wp + 32);
    float4 w1b = *(const float4*)(wp + 36);
    float4 w2a = *(const float4*)(wp + 64);
    float4 w2b = *(const float4*)(wp + 68);

    // ---- stage A slice (fp32 -> bf16, swizzled), coalesced 128B-granule reads ----
    {
        const int r  = tid >> 3;          // row 0..31
        const int c8 = tid & 7;           // float4 column subgroup
        const float* src = A + (size_t)r * HID + ks + c8 * 4;
        char* lb = (char*)As + r * (KSL * 2);
        const int rx = (r & 7) << 4;
#pragma unroll
        for (int i = 0; i < 16; ++i) {
            float4 v = *(const float4*)(src + i * 32);
            unsigned long long pk =
                  (unsigned long long)bf16_rne(v.x)
                | ((unsigned long long)bf16_rne(v.y) << 16)
                | ((unsigned long long)bf16_rne(v.z) << 32)
                | ((unsigned long long)bf16_rne(v.w) << 48);
            int byte = ((c8 + 8 * i) * 8) ^ rx;
            *(unsigned long long*)(lb + byte) = pk;
        }
    }
    __syncthreads();  // the only barrier: LDS written once

    const char* lA0 = (const char*)As + l15 * (KSL * 2);
    const char* lA1 = (const char*)As + (16 + l15) * (KSL * 2);
    const int rswz = l7 << 4;

    f32x4 acc0 = {0.f, 0.f, 0.f, 0.f}, acc1 = {0.f, 0.f, 0.f, 0.f};

#pragma unroll
    for (int kk = 0; kk < NSTEP; ++kk) {
        float4 nA = {}, nB = {};
        if (kk < NSTEP - 3) {
            nA = *(const float4*)(wp + (kk + 3) * 32);
            nB = *(const float4*)(wp + (kk + 3) * 32 + 4);
        }
        const int byte = ((kk * 64) + (lq * 16)) ^ rswz;
        short8 a0 = *(const short8*)(lA0 + byte);
        short8 a1 = *(const short8*)(lA1 + byte);
        short8 b;
        b[0] = (short)bf16_rne(w0a.x); b[1] = (short)bf16_rne(w0a.y);
        b[2] = (short)bf16_rne(w0a.z); b[3] = (short)bf16_rne(w0a.w);
        b[4] = (short)bf16_rne(w0b.x); b[5] = (short)bf16_rne(w0b.y);
        b[6] = (short)bf16_rne(w0b.z); b[7] = (short)bf16_rne(w0b.w);
        acc0 = __builtin_amdgcn_mfma_f32_16x16x32_bf16(a0, b, acc0, 0, 0, 0);
        acc1 = __builtin_amdgcn_mfma_f32_16x16x32_bf16(a1, b, acc1, 0, 0, 0);
        w0a = w1a; w0b = w1b; w1a = w2a; w1b = w2b; w2a = nA; w2b = nB;
    }

    // ---- epilogue: C/D layout col=lane&15, row=(lane>>4)*4+reg (m89-verified) ----
    float* pout = P + (size_t)sl * PART_STRIDE + jcol;
#pragma unroll
    for (int rr = 0; rr < 4; ++rr) {
        pout[(size_t)(lq * 4 + rr) * HID]        = acc0[rr];
        pout[(size_t)(16 + lq * 4 + rr) * HID]   = acc1[rr];
    }
}

// One wave per (b,h,i): fuses the 8-slice q-reduction with 16-key causal attention.
__global__ __launch_bounds__(256)
void attn16_kernel(const float* __restrict__ P,   // q partials [8][32][4096]
                   const float* __restrict__ ck,
                   const float* __restrict__ cv,
                   float* __restrict__ o)          // [32][4096]
{
    const int lane = threadIdx.x & 63;
    const int g = blockIdx.x * 4 + (threadIdx.x >> 6);  // 0..1023
    const int b = g >> 9;
    const int h = (g >> 4) & 31;
    const int i = g & 15;

    const size_t qoff = ((size_t)(b * 16 + i)) * HID + h * 128 + 2 * lane;
    float2 q2 = {0.f, 0.f};
#pragma unroll
    for (int s = 0; s < NSLICE; ++s) {
        float2 p = *(const float2*)(P + (size_t)s * PART_STRIDE + qoff);
        q2.x += p.x; q2.y += p.y;
    }
    const size_t kvoff = ((size_t)(b * 32 + h)) * 2048 * 128 + 2 * lane;
    const float* kp = ck + kvoff;
    const float* vp = cv + kvoff;

    float e[16];
#pragma unroll
    for (int s = 0; s < 16; ++s) {
        float2 k2 = *(const float2*)(kp + (size_t)s * 128);
        float p = q2.x * k2.x + q2.y * k2.y;
#pragma unroll
        for (int m = 32; m >= 1; m >>= 1) p += __shfl_xor(p, m, 64);
        e[s] = (s <= i) ? p * 0.08838834764831845f : -3.4e38f;  // i wave-uniform
    }
    float mx = e[0];
#pragma unroll
    for (int s = 1; s < 16; ++s) mx = fmaxf(mx, e[s]);
    float den = 0.f;
#pragma unroll
    for (int s = 0; s < 16; ++s) { e[s] = __expf(e[s] - mx); den += e[s]; }
    const float inv = 1.0f / den;

    float ox = 0.f, oy = 0.f;
#pragma unroll
    for (int s = 0; s < 16; ++s) {
        float2 v2 = *(const float2*)(vp + (size_t)s * 128);
        ox += e[s] * v2.x;
        oy += e[s] * v2.y;
    }
    float2 res; res.x = ox * inv; res.y = oy * inv;
    *(float2*)(o + qoff) = res;
}

// out[i] = sum over 8 slices of P[s][i]; 32768 float4s.
__global__ __launch_bounds__(256)
void reduce8_kernel(const float* __restrict__ P, float* __restrict__ out)
{
    const int idx = blockIdx.x * 256 + threadIdx.x;  // float4 index
    const float4* p4 = (const float4*)P;
    float4 s = p4[idx];
#pragma unroll
    for (int t = 1; t < NSLICE; ++t) {
        float4 v = p4[idx + t * (PART_STRIDE / 4)];
        s.x += v.x; s.y += v.y; s.z += v.z; s.w += v.w;
    }
    ((float4*)out)[idx] = s;
}

extern "C" void kernel_launch(void* const* d_in, const int* in_sizes, int n_in,
                              void* d_out, int out_size, void* d_ws, size_t ws_size,
                              hipStream_t stream) {
    const float* hidden = (const float*)d_in[0];  // [2][16][4096]
    const float* ck     = (const float*)d_in[3];  // [2][32][2048][128]
    const float* cv     = (const float*)d_in[4];
    const float* Wq     = (const float*)d_in[5];  // [4096][4096]
    const float* Wo     = (const float*)d_in[8];
    float* out  = (float*)d_out;                  // [2][16][4096]
    float* part = (float*)d_ws;                   // [8][32][4096] = 4 MB
    float* abuf = part + NSLICE * PART_STRIDE;    // [32][4096] attn output

    hipLaunchKernelGGL(gemm_mfma,     dim3(512), dim3(256), 0, stream, hidden, Wq, part);
    hipLaunchKernelGGL(attn16_kernel, dim3(256), dim3(256), 0, stream, part, ck, cv, abuf);
    hipLaunchKernelGGL(gemm_mfma,     dim3(512), dim3(256), 0, stream, abuf, Wo, part);
    hipLaunchKernelGGL(reduce8_kernel,dim3(128), dim3(256), 0, stream, part, out);
}

// Round 11
// 37.095 us; speedup vs baseline: 5.5021x; 1.0107x over previous
//
#include <hip/hip_runtime.h>
#include <math.h>

// InfiniteContextAttention — causal mask reaches only keys 0..15 (= compressed_k/v[:,:, :16]).
// Pipeline: q = hidden @ Wq^T -> 16-key causal attention -> out = attn @ Wo^T.
//
// v11 = v7 (37.4us, proven) with EXACTLY ONE change: the W stream is FULLY
// hoisted — all 32 global_load_dwordx4 (16 steps x 2) issue back-to-back right
// after the staging barrier into 32 named float4 regs (~128 VGPR, static
// indices only). Rationale: step compute ~70cyc vs HBM ~900cyc needs queue
// depth ~13 to hide latency; depth-1/3 were equivalent nulls (both << 13).
// Burst is AFTER the barrier so staging A-loads aren't head-of-line blocked
// (in-order vmcnt completion, v5/v6 lesson).

#define HID 4096
#define NROW 32
#define NSLICE 8
#define KSL 512
#define NSTEP 16
#define PART_STRIDE (NROW * HID)  // 131072 floats per slice

typedef __attribute__((ext_vector_type(8))) short short8;
typedef __attribute__((ext_vector_type(4))) float f32x4;

__device__ __forceinline__ unsigned short bf16_rne(float x) {
    union { float f; unsigned u; } c; c.f = x;
    unsigned u = c.u;
    return (unsigned short)((u + 0x7fffu + ((u >> 16) & 1u)) >> 16);
}

__global__ __launch_bounds__(256, 2)
void gemm_mfma(const float* __restrict__ A,   // [32][4096] fp32
               const float* __restrict__ W,   // [4096][4096] fp32
               float* __restrict__ P)         // [8][32][4096] fp32 partials
{
    __shared__ short As[NROW * KSL];  // 32 KB bf16, XOR-swizzled (T2)
    const int tid  = threadIdx.x;
    const int lane = tid & 63;
    const int wv   = tid >> 6;            // wave 0..3 -> 16-col tile
    const int cg   = blockIdx.x & 63;     // column group (64 cols)
    const int sl   = blockIdx.x >> 6;     // K-slice 0..7
    const int ks   = sl * KSL;

    // ---- stage A slice (fp32 -> bf16, swizzled), coalesced 128B-granule reads ----
    {
        const int r  = tid >> 3;          // row 0..31
        const int c8 = tid & 7;           // float4 column subgroup
        const float* src = A + (size_t)r * HID + ks + c8 * 4;
        char* lb = (char*)As + r * (KSL * 2);
        const int rx = (r & 7) << 4;
#pragma unroll
        for (int i = 0; i < 16; ++i) {
            float4 v = *(const float4*)(src + i * 32);
            unsigned long long pk =
                  (unsigned long long)bf16_rne(v.x)
                | ((unsigned long long)bf16_rne(v.y) << 16)
                | ((unsigned long long)bf16_rne(v.z) << 32)
                | ((unsigned long long)bf16_rne(v.w) << 48);
            int byte = ((c8 + 8 * i) * 8) ^ rx;
            *(unsigned long long*)(lb + byte) = pk;
        }
    }
    __syncthreads();  // the only barrier: LDS written once

    const int l15 = lane & 15, lq = lane >> 4, l7 = lane & 7;
    const int jcol = cg * 64 + wv * 16 + l15;
    const float* wp = W + (size_t)jcol * HID + ks + lq * 8;
    const char* lA0 = (const char*)As + l15 * (KSL * 2);
    const char* lA1 = (const char*)As + (16 + l15) * (KSL * 2);
    const int rswz = l7 << 4;

    f32x4 acc0 = {0.f, 0.f, 0.f, 0.f}, acc1 = {0.f, 0.f, 0.f, 0.f};

    // ---- ONLY CHANGE vs v7: full-hoist W burst (32 loads, depth 32 not 3) ----
    float4 wr[2 * NSTEP];
#pragma unroll
    for (int kk = 0; kk < NSTEP; ++kk) {
        wr[2 * kk]     = *(const float4*)(wp + kk * 32);
        wr[2 * kk + 1] = *(const float4*)(wp + kk * 32 + 4);
    }

#pragma unroll
    for (int kk = 0; kk < NSTEP; ++kk) {
        const int byte = ((kk * 64) + (lq * 16)) ^ rswz;
        short8 a0 = *(const short8*)(lA0 + byte);
        short8 a1 = *(const short8*)(lA1 + byte);
        float4 wa = wr[2 * kk];
        float4 wb = wr[2 * kk + 1];
        short8 b;
        b[0] = (short)bf16_rne(wa.x); b[1] = (short)bf16_rne(wa.y);
        b[2] = (short)bf16_rne(wa.z); b[3] = (short)bf16_rne(wa.w);
        b[4] = (short)bf16_rne(wb.x); b[5] = (short)bf16_rne(wb.y);
        b[6] = (short)bf16_rne(wb.z); b[7] = (short)bf16_rne(wb.w);
        acc0 = __builtin_amdgcn_mfma_f32_16x16x32_bf16(a0, b, acc0, 0, 0, 0);
        acc1 = __builtin_amdgcn_mfma_f32_16x16x32_bf16(a1, b, acc1, 0, 0, 0);
    }

    // ---- epilogue: C/D layout col=lane&15, row=(lane>>4)*4+reg (m89-verified) ----
    float* pout = P + (size_t)sl * PART_STRIDE + jcol;
#pragma unroll
    for (int rr = 0; rr < 4; ++rr) {
        pout[(size_t)(lq * 4 + rr) * HID]        = acc0[rr];
        pout[(size_t)(16 + lq * 4 + rr) * HID]   = acc1[rr];
    }
}

// One wave per (b,h,i): fuses the 8-slice q-reduction with 16-key causal attention.
__global__ __launch_bounds__(256)
void attn16_kernel(const float* __restrict__ P,   // q partials [8][32][4096]
                   const float* __restrict__ ck,
                   const float* __restrict__ cv,
                   float* __restrict__ o)          // [32][4096]
{
    const int lane = threadIdx.x & 63;
    const int g = blockIdx.x * 4 + (threadIdx.x >> 6);  // 0..1023
    const int b = g >> 9;
    const int h = (g >> 4) & 31;
    const int i = g & 15;

    const size_t qoff = ((size_t)(b * 16 + i)) * HID + h * 128 + 2 * lane;
    float2 q2 = {0.f, 0.f};
#pragma unroll
    for (int s = 0; s < NSLICE; ++s) {
        float2 p = *(const float2*)(P + (size_t)s * PART_STRIDE + qoff);
        q2.x += p.x; q2.y += p.y;
    }
    const size_t kvoff = ((size_t)(b * 32 + h)) * 2048 * 128 + 2 * lane;
    const float* kp = ck + kvoff;
    const float* vp = cv + kvoff;

    float e[16];
#pragma unroll
    for (int s = 0; s < 16; ++s) {
        float2 k2 = *(const float2*)(kp + (size_t)s * 128);
        float p = q2.x * k2.x + q2.y * k2.y;
#pragma unroll
        for (int m = 32; m >= 1; m >>= 1) p += __shfl_xor(p, m, 64);
        e[s] = (s <= i) ? p * 0.08838834764831845f : -3.4e38f;  // i wave-uniform
    }
    float mx = e[0];
#pragma unroll
    for (int s = 1; s < 16; ++s) mx = fmaxf(mx, e[s]);
    float den = 0.f;
#pragma unroll
    for (int s = 0; s < 16; ++s) { e[s] = __expf(e[s] - mx); den += e[s]; }
    const float inv = 1.0f / den;

    float ox = 0.f, oy = 0.f;
#pragma unroll
    for (int s = 0; s < 16; ++s) {
        float2 v2 = *(const float2*)(vp + (size_t)s * 128);
        ox += e[s] * v2.x;
        oy += e[s] * v2.y;
    }
    float2 res; res.x = ox * inv; res.y = oy * inv;
    *(float2*)(o + qoff) = res;
}

// out[i] = sum over 8 slices of P[s][i]; 32768 float4s.
__global__ __launch_bounds__(256)
void reduce8_kernel(const float* __restrict__ P, float* __restrict__ out)
{
    const int idx = blockIdx.x * 256 + threadIdx.x;  // float4 index
    const float4* p4 = (const float4*)P;
    float4 s = p4[idx];
#pragma unroll
    for (int t = 1; t < NSLICE; ++t) {
        float4 v = p4[idx + t * (PART_STRIDE / 4)];
        s.x += v.x; s.y += v.y; s.z += v.z; s.w += v.w;
    }
    ((float4*)out)[idx] = s;
}

extern "C" void kernel_launch(void* const* d_in, const int* in_sizes, int n_in,
                              void* d_out, int out_size, void* d_ws, size_t ws_size,
                              hipStream_t stream) {
    const float* hidden = (const float*)d_in[0];  // [2][16][4096]
    const float* ck     = (const float*)d_in[3];  // [2][32][2048][128]
    const float* cv     = (const float*)d_in[4];
    const float* Wq     = (const float*)d_in[5];  // [4096][4096]
    const float* Wo     = (const float*)d_in[8];
    float* out  = (float*)d_out;                  // [2][16][4096]
    float* part = (float*)d_ws;                   // [8][32][4096] = 4 MB
    float* abuf = part + NSLICE * PART_STRIDE;    // [32][4096] attn output

    hipLaunchKernelGGL(gemm_mfma,     dim3(512), dim3(256), 0, stream, hidden, Wq, part);
    hipLaunchKernelGGL(attn16_kernel, dim3(256), dim3(256), 0, stream, part, ck, cv, abuf);
    hipLaunchKernelGGL(gemm_mfma,     dim3(512), dim3(256), 0, stream, abuf, Wo, part);
    hipLaunchKernelGGL(reduce8_kernel,dim3(128), dim3(256), 0, stream, part, out);
}